// Round 6
// baseline (99.565 us; speedup 1.0000x reference)
//
#include <hip/hip_runtime.h>
#include <stdint.h>

#define N 4096
#define D 512
#define TILE 128
#define BK 128           // fp8 bytes (=elems) per K-chunk
#define KITERS (D / BK)  // 4
#define NB (N / TILE)    // 32
#define NOFF (NB * (NB - 1) / 2)  // 496 strict-lower block pairs
#define NBLK (NB * (NB + 1) / 2)  // 528 total blocks

typedef float f32x4 __attribute__((ext_vector_type(4)));
typedef int   i32x8 __attribute__((ext_vector_type(8)));
typedef int   i32x4 __attribute__((ext_vector_type(4)));

// ---------------------------------------------------------------------------
// Kernel 1: fp32 -> fp8 e4m3 (OCP) conversion + fp32 row squared-norms.
// One wave per row: 512 elems / 64 lanes = 8 elems/lane (one 8B store).
// Norms are exact fp32; only the Gram term carries fp8 error.
// ---------------------------------------------------------------------------
__global__ __launch_bounds__(256) void prep_kernel(const float* __restrict__ x,
                                                   unsigned char* __restrict__ xq,
                                                   float* __restrict__ sq) {
    int row  = blockIdx.x * 4 + (threadIdx.x >> 6);
    int lane = threadIdx.x & 63;
    const float* xr = x + (size_t)row * D + lane * 8;
    float4 v0 = *reinterpret_cast<const float4*>(xr);
    float4 v1 = *reinterpret_cast<const float4*>(xr + 4);

    int w0 = __builtin_amdgcn_cvt_pk_fp8_f32(v0.x, v0.y, 0, false);
    w0     = __builtin_amdgcn_cvt_pk_fp8_f32(v0.z, v0.w, w0, true);
    int w1 = __builtin_amdgcn_cvt_pk_fp8_f32(v1.x, v1.y, 0, false);
    w1     = __builtin_amdgcn_cvt_pk_fp8_f32(v1.z, v1.w, w1, true);
    reinterpret_cast<int2*>(xq + (size_t)row * D)[lane] = make_int2(w0, w1);

    float s = v0.x * v0.x + v0.y * v0.y + v0.z * v0.z + v0.w * v0.w +
              v1.x * v1.x + v1.y * v1.y + v1.z * v1.z + v1.w * v1.w;
    #pragma unroll
    for (int off = 32; off > 0; off >>= 1) s += __shfl_down(s, off);
    if (lane == 0) sq[row] = s;
}

// ---------------------------------------------------------------------------
// Kernel 2: lower-triangle Gram via MX-scaled fp8 MFMA + fused distance
// epilogue. 128x128 tile, 8 waves (512 thr), each wave owns 32x64.
//
// v7: NO LDS, NO BARRIERS. Evidence chain: v3 (intra-block dbuf) null;
// v4 (+1 block slot) -4us; v5 (2x waves, same barriers) +5us; v6 (2x blocks,
// same barriers) +2us vs v4. Every variant kept the per-iter
// sync->glds->sync(vmcnt(0)) structure; every TLP knob around it saturated.
// The overlooked fact: xq is 2 MB — it fits in ONE XCD's 4 MB L2 (and in
// L3 trivially). Guide common-mistake #7 (m169): don't LDS-stage data that
// cache-fits. So: each lane loads its MFMA fragments DIRECTLY from
// global/L2. One global_load_dwordx4 serves 64 lanes = 16 rows x 64 B = 16
// full cache lines, fully coalesced at line granularity. Per wave per iter:
// 12 loads + 8 MFMA, ZERO synchronization in the entire kernel. Waves drift
// freely; 528 blocks x 8 waves / 1024 SIMDs = 4.1 waves/SIMD hide L2/L3
// latency (acc 32 + frags 48 + misc ~ 110 VGPR fits launch_bounds(512,4)'s
// 128 cap). v5's 8-wave regression was barrier lockstep — no barriers now.
// L2 read amplification ~138 MB total ~ 4 us aggregate @ 34.5 TB/s.
//  - KEEP: diag-last block map, per-wave full/partial/inactive classes,
//    v_sqrt_f32, cached stores (NT cost +9.5us in v2).
// ---------------------------------------------------------------------------
__global__ __launch_bounds__(512, 4) void pairdist_kernel(const unsigned char* __restrict__ xq,
                                                          const float* __restrict__ sq,
                                                          float* __restrict__ out) {
    // Block map: t < NOFF -> strict lower-tri pair (bi > bj); t >= NOFF ->
    // diagonal (bi == bj), launched last (cheapest blocks in any tail round).
    int t = blockIdx.x;
    int bi, bj;
    if (t >= NOFF) {
        bi = bj = t - NOFF;
    } else {
        bi = (int)((sqrtf(8.0f * (float)t + 1.0f) + 1.0f) * 0.5f);
        while (bi * (bi - 1) / 2 > t) bi--;
        while ((bi + 1) * bi / 2 <= t) bi++;
        bj = t - bi * (bi - 1) / 2;
    }

    int tid  = threadIdx.x;
    int w    = tid >> 6;        // wave 0..7
    int lane = tid & 63;
    int quad = lane >> 4;       // 0..3
    int lr   = lane & 15;       // 0..15
    int wm   = w >> 1;          // row strip (0..3) -> 32 rows
    int wn   = w & 1;           // col strip (0..1) -> 64 cols

    int ibase = bi * TILE + wm * 32;
    int jbase = bj * TILE + wn * 64;

    // Wave classes vs the diagonal:
    //  full    : whole 32x64 sub-tile strictly below diag -> no predicate
    //  partial : crosses the diagonal -> predicated stores
    //  inactive: entirely above -> skip everything (no barriers to honor!)
    const bool active = (bi != bj) || (wn == 0) || (wm >= 2);
    const bool fullwave = (bi != bj) || (jbase + 63 < ibase);

    f32x4 acc[2][4];
    #pragma unroll
    for (int mt = 0; mt < 2; mt++)
        #pragma unroll
        for (int nt = 0; nt < 4; nt++)
            acc[mt][nt] = (f32x4)0.0f;

    if (active) {
        // Lane-private fragment source addresses. A frag (mt): row
        // ibase+mt*16+lr, bytes [k0 + quad*32, +32). B frag (nt): row
        // jbase+nt*16+lr, same byte window. Each b128 load: 64 lanes read
        // 16 rows x 64 B = 16 full cache lines -> fully line-coalesced,
        // served by L2/L3 (xq = 2 MB, cache-resident).
        const unsigned char* arow = xq + (size_t)(ibase + lr) * D + quad * 32;
        const unsigned char* brow = xq + (size_t)(jbase + lr) * D + quad * 32;

        #pragma unroll
        for (int it = 0; it < KITERS; it++) {
            const int k0 = it * BK;
            i32x8 af[2], bfr[4];
            #pragma unroll
            for (int mt = 0; mt < 2; mt++) {
                const unsigned char* p = arow + (size_t)(mt * 16) * D + k0;
                i32x4 lo = *reinterpret_cast<const i32x4*>(p);
                i32x4 hi = *reinterpret_cast<const i32x4*>(p + 16);
                af[mt][0] = lo[0]; af[mt][1] = lo[1]; af[mt][2] = lo[2]; af[mt][3] = lo[3];
                af[mt][4] = hi[0]; af[mt][5] = hi[1]; af[mt][6] = hi[2]; af[mt][7] = hi[3];
            }
            #pragma unroll
            for (int nt = 0; nt < 4; nt++) {
                const unsigned char* p = brow + (size_t)(nt * 16) * D + k0;
                i32x4 lo = *reinterpret_cast<const i32x4*>(p);
                i32x4 hi = *reinterpret_cast<const i32x4*>(p + 16);
                bfr[nt][0] = lo[0]; bfr[nt][1] = lo[1]; bfr[nt][2] = lo[2]; bfr[nt][3] = lo[3];
                bfr[nt][4] = hi[0]; bfr[nt][5] = hi[1]; bfr[nt][6] = hi[2]; bfr[nt][7] = hi[3];
            }

            #pragma unroll
            for (int mt = 0; mt < 2; mt++)
                #pragma unroll
                for (int nt = 0; nt < 4; nt++)
                    acc[mt][nt] = __builtin_amdgcn_mfma_scale_f32_16x16x128_f8f6f4(
                        af[mt], bfr[nt], acc[mt][nt],
                        0, 0,                 // cbsz=0 (A fp8 e4m3), blgp=0 (B fp8 e4m3)
                        0, 0x7F7F7F7F,        // A scale: e8m0 127 = x1.0
                        0, 0x7F7F7F7F);       // B scale: x1.0
        }
    }

    if (!active) return;

    // Epilogue: D[m][n] at lane: n = lane&15, m = quad*4 + reg (shape-
    // determined C/D layout — same as 16x16 bf16).
    float sqi[2][4], sqj[4];
    #pragma unroll
    for (int mt = 0; mt < 2; mt++)
        #pragma unroll
        for (int tt = 0; tt < 4; tt++)
            sqi[mt][tt] = sq[ibase + mt * 16 + quad * 4 + tt];
    #pragma unroll
    for (int nt = 0; nt < 4; nt++)
        sqj[nt] = sq[jbase + nt * 16 + lr];

    if (fullwave) {
        // Sub-tile fully below diagonal -> no predicate
        #pragma unroll
        for (int mt = 0; mt < 2; mt++) {
            #pragma unroll
            for (int tt = 0; tt < 4; tt++) {
                int i = ibase + mt * 16 + quad * 4 + tt;
                unsigned rowoff = (unsigned)(i * (i - 1) / 2);
                #pragma unroll
                for (int nt = 0; nt < 4; nt++) {
                    int j = jbase + nt * 16 + lr;
                    float d2 = sqi[mt][tt] + sqj[nt] - 2.0f * acc[mt][nt][tt];
                    out[rowoff + (unsigned)j] = __builtin_amdgcn_sqrtf(fmaxf(d2, 0.0f));
                }
            }
        }
    } else {
        #pragma unroll
        for (int mt = 0; mt < 2; mt++) {
            #pragma unroll
            for (int tt = 0; tt < 4; tt++) {
                int i = ibase + mt * 16 + quad * 4 + tt;
                unsigned rowoff = (unsigned)(i * (i - 1) / 2);
                #pragma unroll
                for (int nt = 0; nt < 4; nt++) {
                    int j = jbase + nt * 16 + lr;
                    if (j < i) {
                        float d2 = sqi[mt][tt] + sqj[nt] - 2.0f * acc[mt][nt][tt];
                        out[rowoff + (unsigned)j] = __builtin_amdgcn_sqrtf(fmaxf(d2, 0.0f));
                    }
                }
            }
        }
    }
}

extern "C" void kernel_launch(void* const* d_in, const int* in_sizes, int n_in,
                              void* d_out, int out_size, void* d_ws, size_t ws_size,
                              hipStream_t stream) {
    const float* x = (const float*)d_in[0];
    float* out = (float*)d_out;

    // Workspace layout: [0, 2MB) fp8 copy of x; then 16KB of fp32 row norms.
    unsigned char* xq = (unsigned char*)d_ws;
    float* sq = (float*)((char*)d_ws + (size_t)N * D);

    prep_kernel<<<N / 4, 256, 0, stream>>>(x, xq, sq);

    pairdist_kernel<<<NBLK, 512, 0, stream>>>(xq, sq, out);
}

// Round 7
// 90.687 us; speedup vs baseline: 1.0979x; 1.0979x over previous
//
#include <hip/hip_runtime.h>
#include <stdint.h>

#define N 4096
#define D 512
#define TILE 128
#define BK 128           // fp8 bytes (=elems) per K-chunk
#define KITERS (D / BK)  // 4
#define NB (N / TILE)    // 32
#define NOFF (NB * (NB - 1) / 2)  // 496 strict-lower block pairs
#define NTILES (NB * (NB + 1) / 2)  // 528 total tiles
#define GRID 768         // persistent blocks: 3 per CU (matches v4 capacity)

typedef float f32x4 __attribute__((ext_vector_type(4)));
typedef int   i32x8 __attribute__((ext_vector_type(8)));
typedef int   i32x4 __attribute__((ext_vector_type(4)));

// ---------------------------------------------------------------------------
// Kernel 1: fp32 -> fp8 e4m3 (OCP) conversion + fp32 row squared-norms.
// One wave per row: 512 elems / 64 lanes = 8 elems/lane (one 8B store).
// Norms are exact fp32; only the Gram term carries fp8 error.
// Also zeroes the pairdist work-queue counter (stream-ordered before k2).
// ---------------------------------------------------------------------------
__global__ __launch_bounds__(256) void prep_kernel(const float* __restrict__ x,
                                                   unsigned char* __restrict__ xq,
                                                   float* __restrict__ sq,
                                                   int* __restrict__ counter) {
    if (blockIdx.x == 0 && threadIdx.x == 0) *counter = 0;

    int row  = blockIdx.x * 4 + (threadIdx.x >> 6);
    int lane = threadIdx.x & 63;
    const float* xr = x + (size_t)row * D + lane * 8;
    float4 v0 = *reinterpret_cast<const float4*>(xr);
    float4 v1 = *reinterpret_cast<const float4*>(xr + 4);

    int w0 = __builtin_amdgcn_cvt_pk_fp8_f32(v0.x, v0.y, 0, false);
    w0     = __builtin_amdgcn_cvt_pk_fp8_f32(v0.z, v0.w, w0, true);
    int w1 = __builtin_amdgcn_cvt_pk_fp8_f32(v1.x, v1.y, 0, false);
    w1     = __builtin_amdgcn_cvt_pk_fp8_f32(v1.z, v1.w, w1, true);
    reinterpret_cast<int2*>(xq + (size_t)row * D)[lane] = make_int2(w0, w1);

    float s = v0.x * v0.x + v0.y * v0.y + v0.z * v0.z + v0.w * v0.w +
              v1.x * v1.x + v1.y * v1.y + v1.z * v1.z + v1.w * v1.w;
    #pragma unroll
    for (int off = 32; off > 0; off >>= 1) s += __shfl_down(s, off);
    if (lane == 0) sq[row] = s;
}

// ---------------------------------------------------------------------------
// Kernel 2: lower-triangle Gram via MX-scaled fp8 MFMA (K=128, unit scales)
// + fused distance epilogue. 128x128 tiles, 4 waves each owning 64x64.
//
// v8 = v4 (best: 79.6, fill-norm ~78.5) + ONE change: DYNAMIC WORK BALANCE.
// Evidence chain: v2 (NT stores) +10; v3 (dbuf) null; v4 (3 slots + af-
// streaming) -4; v5 (8-wave lockstep) +3; v6 (2x smaller tiles) +2;
// v7 (no LDS, direct-global frags) +20 -> the glds+LDS+barrier K-loop is
// near its local optimum; the untouched axis is the 528-tile/256-CU
// imbalance (2.06 tiles/CU non-integral: static capacity-3 puts 2.75
// tile-units on 16 CUs vs 2.0 elsewhere -> makespan 1.35x ideal; v1's
// capacity-2 tail is the same 2.75). Fix: persistent blocks + global
// atomic tile counter. Work-conserving per CU; diag-last order = cheap
// tasks grabbed last (shortest-last greedy). Atomic cost: ~1300
// wave-coalesced same-address adds spread over the kernel, <1 us.
//
// K-loop body, LDS swizzle, af-streaming, epilogue: UNCHANGED from v4.
// ---------------------------------------------------------------------------
__global__ __launch_bounds__(256, 3) void pairdist_kernel(const unsigned char* __restrict__ xq,
                                                          const float* __restrict__ sq,
                                                          float* __restrict__ out,
                                                          int* __restrict__ counter) {
    __shared__ __align__(16) unsigned char As[TILE * BK];  // 16 KB
    __shared__ __align__(16) unsigned char Bs[TILE * BK];  // 16 KB
    __shared__ int tile_t;

    int tid  = threadIdx.x;
    int w    = tid >> 6;        // wave 0..3
    int lane = tid & 63;
    int quad = lane >> 4;       // 0..3
    int lr   = lane & 15;       // 0..15
    int wm   = w >> 1;          // wave row (0..1) -> 64 rows
    int wn   = w & 1;           // wave col (0..1) -> 64 cols

    // Lane-constant staging geometry (tile-independent part).
    int srow   = lane >> 3;                 // 0..7
    int schunk = lane & 7;                  // 16B chunk
    int sw     = ((schunk ^ srow) << 4);    // XOR-swizzled byte offset in row
    unsigned char* la = As + w * 32 * BK;   // wave-uniform LDS bases
    unsigned char* lb = Bs + w * 32 * BK;

    for (;;) {
        if (tid == 0) tile_t = atomicAdd(counter, 1);
        __syncthreads();        // broadcast t; also fences prev tile's ds_reads
        int t = tile_t;
        if (t >= NTILES) return;   // uniform exit across the block

        // Tile map: t < NOFF -> strict lower-tri pair (bi > bj); t >= NOFF ->
        // diagonal (bi == bj), grabbed last (cheapest tasks at the end).
        int bi, bj;
        if (t >= NOFF) {
            bi = bj = t - NOFF;
        } else {
            bi = (int)((sqrtf(8.0f * (float)t + 1.0f) + 1.0f) * 0.5f);
            while (bi * (bi - 1) / 2 > t) bi--;
            while ((bi + 1) * bi / 2 <= t) bi++;
            bj = t - bi * (bi - 1) / 2;
        }

        // Diagonal tiles: wave (wm=0,wn=1) is entirely above the diagonal ->
        // skips fragment reads + MFMAs (still stages rows + hits barriers).
        const bool active = (bi != bj) || (wm >= wn);

        const unsigned char* ga = xq + (size_t)(bi * TILE + w * 32 + srow) * D + sw;
        const unsigned char* gb = xq + (size_t)(bj * TILE + w * 32 + srow) * D + sw;

        f32x4 acc[4][4];
        #pragma unroll
        for (int mt = 0; mt < 4; mt++)
            #pragma unroll
            for (int nt = 0; nt < 4; nt++)
                acc[mt][nt] = (f32x4)0.0f;

        for (int k0 = 0; k0 < D; k0 += BK) {
            if (k0) __syncthreads();   // prev iter's ds_reads done before overwrite
            #pragma unroll
            for (int g = 0; g < 4; g++) {
                __builtin_amdgcn_global_load_lds(
                    (const __attribute__((address_space(1))) void*)(ga + k0 + (size_t)g * 8 * D),
                    (__attribute__((address_space(3))) void*)(la + g * 8 * BK), 16, 0, 0);
                __builtin_amdgcn_global_load_lds(
                    (const __attribute__((address_space(1))) void*)(gb + k0 + (size_t)g * 8 * D),
                    (__attribute__((address_space(3))) void*)(lb + g * 8 * BK), 16, 0, 0);
            }
            __syncthreads();   // drains vmcnt(0): staging visible

            if (active) {
                // Fragment layout (16x16x128 f8f6f4): lane holds
                // A[m=lr][k=quad*32+j], 32 B = 2 x b128. Swizzle: global chunk
                // m lives at LDS chunk m ^ (lr&7); chunks 2q,2q+1 -> c0, c0^16.
                int c0 = (((2 * quad) ^ (lr & 7)) << 4);
                int c1 = c0 ^ 16;

                // B fragments resident for the whole iter (32 VGPR)...
                i32x8 bfr[4];
                #pragma unroll
                for (int nt = 0; nt < 4; nt++) {
                    const unsigned char* rb = Bs + (wn * 64 + nt * 16 + lr) * BK;
                    i32x4 lo = *reinterpret_cast<const i32x4*>(rb + c0);
                    i32x4 hi = *reinterpret_cast<const i32x4*>(rb + c1);
                    bfr[nt][0] = lo[0]; bfr[nt][1] = lo[1]; bfr[nt][2] = lo[2]; bfr[nt][3] = lo[3];
                    bfr[nt][4] = hi[0]; bfr[nt][5] = hi[1]; bfr[nt][6] = hi[2]; bfr[nt][7] = hi[3];
                }
                // ...A fragment streamed per-mt (8 VGPR live at a time); the
                // compiler pipelines mt+1's ds_reads under mt's 4 MFMAs.
                #pragma unroll
                for (int mt = 0; mt < 4; mt++) {
                    const unsigned char* rb = As + (wm * 64 + mt * 16 + lr) * BK;
                    i32x4 lo = *reinterpret_cast<const i32x4*>(rb + c0);
                    i32x4 hi = *reinterpret_cast<const i32x4*>(rb + c1);
                    i32x8 af;
                    af[0] = lo[0]; af[1] = lo[1]; af[2] = lo[2]; af[3] = lo[3];
                    af[4] = hi[0]; af[5] = hi[1]; af[6] = hi[2]; af[7] = hi[3];
                    #pragma unroll
                    for (int nt = 0; nt < 4; nt++)
                        acc[mt][nt] = __builtin_amdgcn_mfma_scale_f32_16x16x128_f8f6f4(
                            af, bfr[nt], acc[mt][nt],
                            0, 0,                 // cbsz=0 (A fp8 e4m3), blgp=0 (B e4m3)
                            0, 0x7F7F7F7F,        // A scale: e8m0 127 = x1.0
                            0, 0x7F7F7F7F);       // B scale: x1.0
                }
            }
        }

        if (active) {
            // Epilogue: D[m][n] at lane: n = lane&15, m = quad*4 + reg (shape-
            // determined C/D layout — same as 16x16 bf16).
            int ibase = bi * TILE + wm * 64;
            int jbase = bj * TILE + wn * 64;

            float sqi[4][4], sqj[4];
            #pragma unroll
            for (int mt = 0; mt < 4; mt++)
                #pragma unroll
                for (int tt = 0; tt < 4; tt++)
                    sqi[mt][tt] = sq[ibase + mt * 16 + quad * 4 + tt];
            #pragma unroll
            for (int nt = 0; nt < 4; nt++)
                sqj[nt] = sq[jbase + nt * 16 + lr];

            if (bi != bj) {
                // Fully-below-diagonal tile: all j < i -> no predicate
                #pragma unroll
                for (int mt = 0; mt < 4; mt++) {
                    #pragma unroll
                    for (int tt = 0; tt < 4; tt++) {
                        int i = ibase + mt * 16 + quad * 4 + tt;
                        unsigned rowoff = (unsigned)(i * (i - 1) / 2);
                        #pragma unroll
                        for (int nt = 0; nt < 4; nt++) {
                            int j = jbase + nt * 16 + lr;
                            float d2 = sqi[mt][tt] + sqj[nt] - 2.0f * acc[mt][nt][tt];
                            out[rowoff + (unsigned)j] = __builtin_amdgcn_sqrtf(fmaxf(d2, 0.0f));
                        }
                    }
                }
            } else {
                #pragma unroll
                for (int mt = 0; mt < 4; mt++) {
                    #pragma unroll
                    for (int tt = 0; tt < 4; tt++) {
                        int i = ibase + mt * 16 + quad * 4 + tt;
                        unsigned rowoff = (unsigned)(i * (i - 1) / 2);
                        #pragma unroll
                        for (int nt = 0; nt < 4; nt++) {
                            int j = jbase + nt * 16 + lr;
                            if (j < i) {
                                float d2 = sqi[mt][tt] + sqj[nt] - 2.0f * acc[mt][nt][tt];
                                out[rowoff + (unsigned)j] = __builtin_amdgcn_sqrtf(fmaxf(d2, 0.0f));
                            }
                        }
                    }
                }
            }
        }
    }
}

extern "C" void kernel_launch(void* const* d_in, const int* in_sizes, int n_in,
                              void* d_out, int out_size, void* d_ws, size_t ws_size,
                              hipStream_t stream) {
    const float* x = (const float*)d_in[0];
    float* out = (float*)d_out;

    // Workspace: [0, 2MB) fp8 copy of x; [2MB, 2MB+16KB) fp32 row norms;
    // then a 4B work-queue counter (zeroed by prep each iteration).
    unsigned char* xq = (unsigned char*)d_ws;
    float* sq = (float*)((char*)d_ws + (size_t)N * D);
    int* counter = (int*)((char*)d_ws + (size_t)N * D + (size_t)N * sizeof(float));

    prep_kernel<<<N / 4, 256, 0, stream>>>(x, xq, sq, counter);

    pairdist_kernel<<<GRID, 256, 0, stream>>>(xq, sq, out, counter);
}

// Round 8
// 80.594 us; speedup vs baseline: 1.2354x; 1.1252x over previous
//
#include <hip/hip_runtime.h>
#include <stdint.h>

#define N 4096
#define D 512
#define BK 128            // fp8 bytes (=elems) per K-chunk
#define KITERS (D / BK)   // 4
#define WTM 32            // wave-tile rows
#define WTN 64            // wave-tile cols
#define NGI (N / WTM)     // 128 row groups
#define NTW 4160          // wave-tiles covering the lower triangle (incl. diag)
#define GRID (NTW / 4)    // 1040 blocks x 4 waves

typedef float f32x4 __attribute__((ext_vector_type(4)));
typedef int   i32x8 __attribute__((ext_vector_type(8)));
typedef int   i32x4 __attribute__((ext_vector_type(4)));

// ---------------------------------------------------------------------------
// Kernel 1: fp32 -> fp8 e4m3 (OCP) conversion + fp32 row squared-norms.
// One wave per row: 512 elems / 64 lanes = 8 elems/lane (one 8B store).
// Norms are exact fp32; only the Gram term carries fp8 error.
// ---------------------------------------------------------------------------
__global__ __launch_bounds__(256) void prep_kernel(const float* __restrict__ x,
                                                   unsigned char* __restrict__ xq,
                                                   float* __restrict__ sq) {
    int row  = blockIdx.x * 4 + (threadIdx.x >> 6);
    int lane = threadIdx.x & 63;
    const float* xr = x + (size_t)row * D + lane * 8;
    float4 v0 = *reinterpret_cast<const float4*>(xr);
    float4 v1 = *reinterpret_cast<const float4*>(xr + 4);

    int w0 = __builtin_amdgcn_cvt_pk_fp8_f32(v0.x, v0.y, 0, false);
    w0     = __builtin_amdgcn_cvt_pk_fp8_f32(v0.z, v0.w, w0, true);
    int w1 = __builtin_amdgcn_cvt_pk_fp8_f32(v1.x, v1.y, 0, false);
    w1     = __builtin_amdgcn_cvt_pk_fp8_f32(v1.z, v1.w, w1, true);
    reinterpret_cast<int2*>(xq + (size_t)row * D)[lane] = make_int2(w0, w1);

    float s = v0.x * v0.x + v0.y * v0.y + v0.z * v0.z + v0.w * v0.w +
              v1.x * v1.x + v1.y * v1.y + v1.z * v1.z + v1.w * v1.w;
    #pragma unroll
    for (int off = 32; off > 0; off >>= 1) s += __shfl_down(s, off);
    if (lane == 0) sq[row] = s;
}

// ---------------------------------------------------------------------------
// Kernel 2, v9: WAVE-PRIVATE staging — zero barriers, zero inter-wave
// coupling, same proven glds->LDS->MFMA data path.
//
// Evidence chain: v5 (more waves, barrier-lockstep) +3; v8 (dynamic queue,
// intra-block serialization) +11; v7 (no LDS, direct-global frags) +20;
// v3/v6 (barrier rearrangements) null. Untried quadrant: keep the full-line
// glds staging (v7's failure was half-line direct fragment loads), drop ALL
// synchronization (v5/v8's failure was coupling).
//  - Each wave owns an independent 32x64 output tile. 4160 tiles total.
//  - Private 12 KB LDS per wave (A 4 KB + B 8 KB); 48 KB/block -> 3
//    blocks/CU -> 12 fully-independent waves/CU drifting freely; store
//    bursts, stage stalls and MFMA phases interleave across waves.
//  - Per K-iter: 12 glds (8 full cache lines each) -> s_waitcnt vmcnt(0)
//    (wave-local, NOT a barrier drain) -> swizzled ds_read frags -> 8 MFMA.
//  - lgkmcnt(0) + sched_barrier(0) before re-staging the single buffer
//    (ds_read/glds-write have no HW ordering; guide rule #18 for hoisting).
//  - sq[] preloaded under iter-0's stage latency (12 VGPR, budget fine).
//  - XOR swizzle unchanged: LDS slot (row,chunk) holds global chunk
//    (chunk ^ (row&7)); frag read offsets c0 = ((2q)^(lr&7))<<4, c1 = c0^16.
//
// Tile map: row-group gi (32 rows) has floor(gi/2)+1 col-panels (64 cols).
// Cumulative: C(2a) = a(a+1), C(2a+1) = (a+1)^2. Partial (diagonal) tile
// iff jg == gi>>1 (the last panel of each row group).
// ---------------------------------------------------------------------------
__global__ __launch_bounds__(256, 3) void pairdist_kernel(const unsigned char* __restrict__ xq,
                                                          const float* __restrict__ sq,
                                                          float* __restrict__ out) {
    __shared__ __align__(16) unsigned char lds[4][12 * 1024];  // 48 KB

    int tid  = threadIdx.x;
    int w    = tid >> 6;        // wave 0..3 (independent tiles)
    int lane = tid & 63;
    int quad = lane >> 4;       // 0..3
    int lr   = lane & 15;       // 0..15

    int t = blockIdx.x * 4 + w;            // wave-tile id, 0..4159

    // t -> (gi, jg)
    int a = (int)((sqrtf(4.0f * (float)t + 1.0f) - 1.0f) * 0.5f);
    while (a * (a + 1) > t) a--;
    while ((a + 1) * (a + 2) <= t) a++;
    int gi, jg;
    int r0 = t - a * (a + 1);
    if (r0 <= a) { gi = 2 * a;     jg = r0; }
    else         { gi = 2 * a + 1; jg = t - (a + 1) * (a + 1); }
    const bool partial = (jg == (gi >> 1));

    int ibase = gi * WTM;
    int jbase = jg * WTN;

    // Staging geometry: lane l -> row l>>3, LDS chunk l&7; global source
    // chunk = (l&7) ^ (l>>3) (the XOR swizzle). Each glds covers 8 rows =
    // 8 full 128B cache lines.
    int srow   = lane >> 3;
    int schunk = lane & 7;
    int sw     = ((schunk ^ srow) << 4);
    const unsigned char* ga = xq + (size_t)(ibase + srow) * D + sw;
    const unsigned char* gb = xq + (size_t)(jbase + srow) * D + sw;
    unsigned char* la = &lds[w][0];         // 4 KB: A rows ibase..+31
    unsigned char* lb = &lds[w][4 * 1024];  // 8 KB: B rows jbase..+63

    // Fragment read offsets within a row (swizzled).
    const int c0 = (((2 * quad) ^ (lr & 7)) << 4);
    const int c1 = c0 ^ 16;

    f32x4 acc[2][4];
    #pragma unroll
    for (int mt = 0; mt < 2; mt++)
        #pragma unroll
        for (int nt = 0; nt < 4; nt++)
            acc[mt][nt] = (f32x4)0.0f;

    // ---- iter 0 stage issue ----
    #pragma unroll
    for (int g = 0; g < 4; g++)
        __builtin_amdgcn_global_load_lds(
            (const __attribute__((address_space(1))) void*)(ga + (size_t)g * 8 * D),
            (__attribute__((address_space(3))) void*)(la + g * 8 * BK), 16, 0, 0);
    #pragma unroll
    for (int g = 0; g < 8; g++)
        __builtin_amdgcn_global_load_lds(
            (const __attribute__((address_space(1))) void*)(gb + (size_t)g * 8 * D),
            (__attribute__((address_space(3))) void*)(lb + g * 8 * BK), 16, 0, 0);

    // sq preload: latency hides under the stage in flight.
    float sqi[2][4], sqj[4];
    #pragma unroll
    for (int mt = 0; mt < 2; mt++)
        #pragma unroll
        for (int tt = 0; tt < 4; tt++)
            sqi[mt][tt] = sq[ibase + mt * 16 + quad * 4 + tt];
    #pragma unroll
    for (int nt = 0; nt < 4; nt++)
        sqj[nt] = sq[jbase + nt * 16 + lr];

    #pragma unroll
    for (int it = 0; it < KITERS; it++) {
        // Wait for this wave's stage (vmcnt(0); exp=7, lgkm=15: no-wait).
        __builtin_amdgcn_s_waitcnt(0x0F70);
        __builtin_amdgcn_sched_barrier(0);   // no ds_read hoisting above the wait

        i32x8 af[2], bfr[4];
        #pragma unroll
        for (int mt = 0; mt < 2; mt++) {
            const unsigned char* rb = la + (mt * 16 + lr) * BK;
            i32x4 lo = *reinterpret_cast<const i32x4*>(rb + c0);
            i32x4 hi = *reinterpret_cast<const i32x4*>(rb + c1);
            af[mt][0] = lo[0]; af[mt][1] = lo[1]; af[mt][2] = lo[2]; af[mt][3] = lo[3];
            af[mt][4] = hi[0]; af[mt][5] = hi[1]; af[mt][6] = hi[2]; af[mt][7] = hi[3];
        }
        #pragma unroll
        for (int nt = 0; nt < 4; nt++) {
            const unsigned char* rb = lb + (nt * 16 + lr) * BK;
            i32x4 lo = *reinterpret_cast<const i32x4*>(rb + c0);
            i32x4 hi = *reinterpret_cast<const i32x4*>(rb + c1);
            bfr[nt][0] = lo[0]; bfr[nt][1] = lo[1]; bfr[nt][2] = lo[2]; bfr[nt][3] = lo[3];
            bfr[nt][4] = hi[0]; bfr[nt][5] = hi[1]; bfr[nt][6] = hi[2]; bfr[nt][7] = hi[3];
        }

        if (it + 1 < KITERS) {
            // All frag ds_reads must have landed before overwriting the
            // buffer (glds LDS-writes are not ordered vs in-flight ds_read).
            // lgkmcnt(0); vmcnt=63, exp=7: no-wait.
            __builtin_amdgcn_s_waitcnt(0xC07F);
            __builtin_amdgcn_sched_barrier(0);
            const int k0 = (it + 1) * BK;
            #pragma unroll
            for (int g = 0; g < 4; g++)
                __builtin_amdgcn_global_load_lds(
                    (const __attribute__((address_space(1))) void*)(ga + k0 + (size_t)g * 8 * D),
                    (__attribute__((address_space(3))) void*)(la + g * 8 * BK), 16, 0, 0);
            #pragma unroll
            for (int g = 0; g < 8; g++)
                __builtin_amdgcn_global_load_lds(
                    (const __attribute__((address_space(1))) void*)(gb + k0 + (size_t)g * 8 * D),
                    (__attribute__((address_space(3))) void*)(lb + g * 8 * BK), 16, 0, 0);
        }

        #pragma unroll
        for (int mt = 0; mt < 2; mt++)
            #pragma unroll
            for (int nt = 0; nt < 4; nt++)
                acc[mt][nt] = __builtin_amdgcn_mfma_scale_f32_16x16x128_f8f6f4(
                    af[mt], bfr[nt], acc[mt][nt],
                    0, 0,                 // cbsz=0 (A fp8 e4m3), blgp=0 (B fp8 e4m3)
                    0, 0x7F7F7F7F,        // A scale: e8m0 127 = x1.0
                    0, 0x7F7F7F7F);       // B scale: x1.0
    }

    // Epilogue: D[m][n] at lane: n = lane&15, m = quad*4 + reg (shape-
    // determined C/D layout — same as 16x16 bf16).
    if (!partial) {
        #pragma unroll
        for (int mt = 0; mt < 2; mt++) {
            #pragma unroll
            for (int tt = 0; tt < 4; tt++) {
                int i = ibase + mt * 16 + quad * 4 + tt;
                unsigned rowoff = (unsigned)(i * (i - 1) / 2);
                #pragma unroll
                for (int nt = 0; nt < 4; nt++) {
                    int j = jbase + nt * 16 + lr;
                    float d2 = sqi[mt][tt] + sqj[nt] - 2.0f * acc[mt][nt][tt];
                    out[rowoff + (unsigned)j] = __builtin_amdgcn_sqrtf(fmaxf(d2, 0.0f));
                }
            }
        }
    } else {
        #pragma unroll
        for (int mt = 0; mt < 2; mt++) {
            #pragma unroll
            for (int tt = 0; tt < 4; tt++) {
                int i = ibase + mt * 16 + quad * 4 + tt;
                unsigned rowoff = (unsigned)(i * (i - 1) / 2);
                #pragma unroll
                for (int nt = 0; nt < 4; nt++) {
                    int j = jbase + nt * 16 + lr;
                    if (j < i) {
                        float d2 = sqi[mt][tt] + sqj[nt] - 2.0f * acc[mt][nt][tt];
                        out[rowoff + (unsigned)j] = __builtin_amdgcn_sqrtf(fmaxf(d2, 0.0f));
                    }
                }
            }
        }
    }
}

extern "C" void kernel_launch(void* const* d_in, const int* in_sizes, int n_in,
                              void* d_out, int out_size, void* d_ws, size_t ws_size,
                              hipStream_t stream) {
    const float* x = (const float*)d_in[0];
    float* out = (float*)d_out;

    // Workspace layout: [0, 2MB) fp8 copy of x; then 16KB of fp32 row norms.
    unsigned char* xq = (unsigned char*)d_ws;
    float* sq = (float*)((char*)d_ws + (size_t)N * D);

    prep_kernel<<<N / 4, 256, 0, stream>>>(x, xq, sq);

    pairdist_kernel<<<GRID, 256, 0, stream>>>(xq, sq, out);
}